// Round 17
// baseline (355.214 us; speedup 1.0000x reference)
//
#include <hip/hip_runtime.h>
#include <hip/hip_bf16.h>
#include <cstdint>
#include <cstddef>

typedef __attribute__((ext_vector_type(8))) short bf16x8;
typedef __attribute__((ext_vector_type(4))) float f32x4;

#define BB 32
#define NN 1024
#define CC 768
#define NHH 12
#define HDD 64
#define KKK 9
#define MM (BB * NN)   /* 32768 */
#define KN2 1664       /* v(768) | xq(768) | scores(108 pad 128) */
#define PMDD 1536
#define CMDD 1536
#define BK 64

#define XBF_BLOCKS 12288   /* MM*CC/(256*8) */
#define WT_BLOCKS 1152     /* 48 j-tiles x 24 c-tiles (v+xq = 1536 rows) */
#define WT2_BLOCKS 2880
#define SW_BLOCKS 128      /* 108 score rows + 20 zero-pad rows */
#define TMC 16             /* token-mix j-chunks */

__device__ __forceinline__ float bfbits2f(short s) {
  union { uint32_t u; float f; } cv;
  cv.u = ((uint32_t)(uint16_t)s) << 16;
  return cv.f;
}
__device__ __forceinline__ short f2bf(float f) {
  union { float f; uint32_t u; } cv;
  cv.f = f;
  uint32_t u = cv.u;
  uint32_t r = (u + 0x7fffu + ((u >> 16) & 1u)) >> 16;
  return (short)r;
}
__device__ __forceinline__ float gelu_f(float x) {
  return 0.5f * x * (1.0f + erff(x * 0.7071067811865476f));
}

typedef const __attribute__((address_space(1))) uint32_t* gp1_t;
typedef __attribute__((address_space(3))) uint32_t* lp3_t;
__device__ __forceinline__ void gload16(const short* g, const short* l) {
  __builtin_amdgcn_global_load_lds((gp1_t)(uintptr_t)(const void*)g,
                                   (lp3_t)(uint32_t)(uintptr_t)(const void*)l,
                                   16, 0, 0);
}

// ---- prep: x->bf16 + Wt build (v^T|xq^T|S_w) + small-W transposes ---------
__global__ __launch_bounds__(256) void prep_kernel(
    const float* __restrict__ x, short* __restrict__ xb,
    const float* __restrict__ kv_w, const float* __restrict__ projq_w,
    short* __restrict__ Wt,
    const float* __restrict__ proj_w, const float* __restrict__ cm1_w,
    const float* __restrict__ cm2_w,
    short* __restrict__ WpT, short* __restrict__ Wc1T, short* __restrict__ Wc2T,
    const float* __restrict__ kern, const float* __restrict__ ln_g,
    const float* __restrict__ ln_b)
{
  __shared__ float smem[1056];
  const int bx = blockIdx.x;
  const int tid = threadIdx.x;
  if (bx < XBF_BLOCKS) {
    const int i = (bx * 256 + tid) * 8;
    f32x4 a = *(const f32x4*)&x[i];
    f32x4 b = *(const f32x4*)&x[i + 4];
    bf16x8 o;
#pragma unroll
    for (int e = 0; e < 4; e++) { o[e] = f2bf(a[e]); o[e + 4] = f2bf(b[e]); }
    *(bf16x8*)&xb[i] = o;
    return;
  }
  if (bx < XBF_BLOCKS + WT_BLOCKS) {
    int b2 = bx - XBF_BLOCKS;
    int j0 = (b2 % 48) * 32;
    int c0 = (b2 / 48) * 32;
    const float* src; int ldj, jj;
    if (j0 < 768) { src = kv_w; ldj = 1536; jj = 768 + j0; }
    else          { src = projq_w; ldj = 768; jj = j0 - 768; }
    const int tx = tid & 31, ty = tid >> 5;
#pragma unroll
    for (int r = 0; r < 4; r++) {
      int cl = ty + r * 8;
      smem[cl * 33 + tx] = src[(size_t)(c0 + cl) * ldj + jj + tx];
    }
    __syncthreads();
#pragma unroll
    for (int r = 0; r < 4; r++) {
      int jl = ty + r * 8;
      Wt[(size_t)(j0 + jl) * CC + c0 + tx] = f2bf(smem[tx * 33 + jl]);
    }
    return;
  }
  if (bx < XBF_BLOCKS + WT_BLOCKS + WT2_BLOCKS) {
    int b2 = bx - XBF_BLOCKS - WT_BLOCKS;
    const float* src; short* dst; int ldj, ldc, j0, c0;
    if (b2 < 576)        { src = proj_w; dst = WpT;  ldj = 768;  ldc = 768;
                           j0 = (b2 % 24) * 32; c0 = (b2 / 24) * 32; }
    else if (b2 < 1728)  { b2 -= 576; src = cm1_w; dst = Wc1T; ldj = 1536; ldc = 768;
                           j0 = (b2 % 48) * 32; c0 = (b2 / 48) * 32; }
    else                 { b2 -= 1728; src = cm2_w; dst = Wc2T; ldj = 768; ldc = 1536;
                           j0 = (b2 % 24) * 32; c0 = (b2 / 24) * 32; }
    const int tx = tid & 31, ty = tid >> 5;
#pragma unroll
    for (int r = 0; r < 4; r++) {
      int cl = ty + r * 8;
      smem[cl * 33 + tx] = src[(size_t)(c0 + cl) * ldj + j0 + tx];
    }
    __syncthreads();
#pragma unroll
    for (int r = 0; r < 4; r++) {
      int jl = ty + r * 8;
      dst[(size_t)(j0 + jl) * ldc + c0 + tx] = f2bf(smem[tx * 33 + jl]);
    }
    return;
  }
  // SW blocks: Wt rows 1536+s = SCALE * (LN(kern)[q] row_h) @ Wk_h^T
  {
    const int s = bx - (XBF_BLOCKS + WT_BLOCKS + WT2_BLOCKS);
    if (s >= 108) {
      const size_t r = (size_t)(1536 + s) * CC;
      Wt[r + tid] = 0; Wt[r + tid + 256] = 0; Wt[r + tid + 512] = 0;
      return;
    }
    const int h = s / 9, q = s % 9;
    float* red = smem;
    const size_t base = (size_t)q * CC;
    float x0 = kern[base + tid];
    float x1 = kern[base + tid + 256];
    float x2 = kern[base + tid + 512];
    red[tid] = x0 + x1 + x2;
    __syncthreads();
    for (int st = 128; st > 0; st >>= 1) { if (tid < st) red[tid] += red[tid + st]; __syncthreads(); }
    float mean = red[0] * (1.0f / 768.0f);
    __syncthreads();
    float d0 = x0 - mean, d1 = x1 - mean, d2 = x2 - mean;
    red[tid] = d0 * d0 + d1 * d1 + d2 * d2;
    __syncthreads();
    for (int st = 128; st > 0; st >>= 1) { if (tid < st) red[tid] += red[tid + st]; __syncthreads(); }
    float rstd = rsqrtf(red[0] * (1.0f / 768.0f) + 1e-6f);
    __syncthreads();
    smem[tid]       = d0 * rstd * ln_g[tid]       + ln_b[tid];
    smem[tid + 256] = d1 * rstd * ln_g[tid + 256] + ln_b[tid + 256];
    smem[tid + 512] = d2 * rstd * ln_g[tid + 512] + ln_b[tid + 512];
    __syncthreads();
#pragma unroll
    for (int k = 0; k < 3; k++) {
      const int cc = tid + k * 256;
      const float* kw = &kv_w[(size_t)cc * 1536 + h * HDD];
      float acc = 0.f;
#pragma unroll
      for (int dd = 0; dd < HDD; dd++) acc += smem[h * HDD + dd] * kw[dd];
      Wt[(size_t)(1536 + s) * CC + cc] = f2bf(acc * 0.125f);
    }
  }
}

// ---- big GEMM: 128x128 tile, 2 waves, per-wave 128x64, dbuf + vmcnt(16) ---
__global__ __launch_bounds__(128) void gemm_bt_kernel(
    const short* __restrict__ A,     // [MM][768] bf16
    const short* __restrict__ Bt,    // [1664][768] bf16 (B^T)
    short* __restrict__ C)           // [MM][1664] bf16 (v|xq|scores)
{
  __shared__ short As[2][128 * BK];
  __shared__ short Bs[2][128 * BK];
  const int tid = threadIdx.x;
  const int wave = tid >> 6, lane = tid & 63;
  const int lid = blockIdx.x;                    // 3328 = 8 * 416
  const int wid = (lid & 7) * 416 + (lid >> 3);
  const int bn = (wid % 13) * 128;
  const int bm = (wid / 13) * 128;
  const int wno = wave * 64;
  const int lrow = lane & 15;
  const int kgrp = lane >> 4;
  const int sr = tid >> 3;           // 0..15
  const int ss = tid & 7;
  const int slotG = ss ^ (sr & 7);   // row&7 == sr&7 for rows i*16+sr
  const short* gA = A + (size_t)(bm + sr) * CC + slotG * 8;
  const short* gB = Bt + (size_t)(bn + sr) * CC + slotG * 8;
  const int rs0 = kgrp ^ (lrow & 7);
  const int rs1 = (4 + kgrp) ^ (lrow & 7);
  f32x4 acc[8][4];
#pragma unroll
  for (int m = 0; m < 8; m++)
#pragma unroll
    for (int n = 0; n < 4; n++) acc[m][n] = (f32x4){0.f, 0.f, 0.f, 0.f};

#define STAGE(bb, k0)                                                          \
  {                                                                            \
    _Pragma("unroll")                                                          \
    for (int i = 0; i < 8; i++) {                                              \
      gload16(gA + (size_t)(i * 16) * CC + (k0),                               \
              &As[bb][(i * 16 + sr) * BK + ss * 8]);                           \
      gload16(gB + (size_t)(i * 16) * CC + (k0),                               \
              &Bs[bb][(i * 16 + sr) * BK + ss * 8]);                           \
    }                                                                          \
  }

  STAGE(0, 0);
  for (int t = 0; t < 12; ++t) {
    const int cur = t & 1;
    if (t < 11) STAGE(cur ^ 1, (t + 1) * BK);
    __builtin_amdgcn_sched_barrier(0);
    if (t < 11) asm volatile("s_waitcnt vmcnt(16)" ::: "memory");
    else        asm volatile("s_waitcnt vmcnt(0)" ::: "memory");
    __builtin_amdgcn_s_barrier();
    __builtin_amdgcn_sched_barrier(0);
#pragma unroll
    for (int kh = 0; kh < 2; kh++) {
      const int rs = kh ? rs1 : rs0;
      bf16x8 af[8], bfr[4];
#pragma unroll
      for (int m = 0; m < 8; m++)
        af[m] = *(const bf16x8*)&As[cur][(m * 16 + lrow) * BK + rs * 8];
#pragma unroll
      for (int n = 0; n < 4; n++)
        bfr[n] = *(const bf16x8*)&Bs[cur][(wno + n * 16 + lrow) * BK + rs * 8];
      __builtin_amdgcn_s_setprio(1);
#pragma unroll
      for (int m = 0; m < 8; m++)
#pragma unroll
        for (int n = 0; n < 4; n++)
          acc[m][n] = __builtin_amdgcn_mfma_f32_16x16x32_bf16(af[m], bfr[n], acc[m][n], 0, 0, 0);
      __builtin_amdgcn_s_setprio(0);
    }
    __builtin_amdgcn_sched_barrier(0);
    __builtin_amdgcn_s_barrier();   // reads of buf[cur] consumed before restage
  }
#undef STAGE
#pragma unroll
  for (int m = 0; m < 8; m++)
#pragma unroll
    for (int n = 0; n < 4; n++)
#pragma unroll
      for (int r = 0; r < 4; r++) {
        const int row = bm + m * 16 + kgrp * 4 + r;
        const int col = bn + wno + n * 16 + lrow;
        C[(size_t)row * KN2 + col] = f2bf(acc[m][n][r]);
      }
}

// ---------------- mini MFMA GEMM: 96x128, BK=64, dbuf + counted vmcnt ------
template <int EP>
__global__ __launch_bounds__(256) void mfma96_kernel(
    const short* __restrict__ A,    // [288][K] bf16
    const short* __restrict__ Bt,   // [N][K] bf16
    int K, int ldn,
    const float* __restrict__ bias,
    const float* __restrict__ kern,
    float* __restrict__ Cf,
    short* __restrict__ Cb)
{
  __shared__ short As[2][96 * BK];
  __shared__ short Bs[2][128 * BK];
  const int tid = threadIdx.x;
  const int wave = tid >> 6, lane = tid & 63;
  const int bm = blockIdx.x * 96;
  const int bn = blockIdx.y * 128;
  const int wmo = (wave >> 1) * 48;
  const int wno = (wave & 1) * 64;
  const int lrow = lane & 15;
  const int kgrp = lane >> 4;
  const int sr = tid >> 3;
  const int ss = tid & 7;
  const int rs0 = kgrp ^ (lrow & 7);
  const int rs1 = (4 + kgrp) ^ (lrow & 7);
  f32x4 acc[3][4];
#pragma unroll
  for (int i = 0; i < 3; i++)
#pragma unroll
    for (int j = 0; j < 4; j++) acc[i][j] = (f32x4){0.f, 0.f, 0.f, 0.f};

#define STAGEM(bb, k0)                                                         \
  {                                                                            \
    _Pragma("unroll")                                                          \
    for (int i = 0; i < 3; i++) {                                              \
      const int r = i * 32 + sr;                                               \
      const int sg = ss ^ (r & 7);                                             \
      gload16(A + (size_t)(bm + r) * K + (k0) + sg * 8,                        \
              &As[bb][r * BK + ss * 8]);                                       \
    }                                                                          \
    _Pragma("unroll")                                                          \
    for (int i = 0; i < 4; i++) {                                              \
      const int r = i * 32 + sr;                                               \
      const int sg = ss ^ (r & 7);                                             \
      gload16(Bt + (size_t)(bn + r) * K + (k0) + sg * 8,                       \
              &Bs[bb][r * BK + ss * 8]);                                       \
    }                                                                          \
  }

  const int nt = K / BK;
  STAGEM(0, 0);
  for (int t = 0; t < nt; ++t) {
    const int cur = t & 1;
    if (t < nt - 1) STAGEM(cur ^ 1, (t + 1) * BK);
    __builtin_amdgcn_sched_barrier(0);
    if (t < nt - 1) asm volatile("s_waitcnt vmcnt(7)" ::: "memory");
    else            asm volatile("s_waitcnt vmcnt(0)" ::: "memory");
    __builtin_amdgcn_s_barrier();
    __builtin_amdgcn_sched_barrier(0);
#pragma unroll
    for (int kh = 0; kh < 2; kh++) {
      const int rs = kh ? rs1 : rs0;
      bf16x8 af[3], bfr[4];
#pragma unroll
      for (int m = 0; m < 3; m++)
        af[m] = *(const bf16x8*)&As[cur][(wmo + m * 16 + lrow) * BK + rs * 8];
#pragma unroll
      for (int n = 0; n < 4; n++)
        bfr[n] = *(const bf16x8*)&Bs[cur][(wno + n * 16 + lrow) * BK + rs * 8];
#pragma unroll
      for (int m = 0; m < 3; m++)
#pragma unroll
        for (int n = 0; n < 4; n++)
          acc[m][n] = __builtin_amdgcn_mfma_f32_16x16x32_bf16(af[m], bfr[n], acc[m][n], 0, 0, 0);
    }
    __builtin_amdgcn_sched_barrier(0);
    __builtin_amdgcn_s_barrier();
  }
#undef STAGEM
#pragma unroll
  for (int m = 0; m < 3; m++)
#pragma unroll
    for (int n = 0; n < 4; n++)
#pragma unroll
      for (int r = 0; r < 4; r++) {
        const int row = bm + wmo + m * 16 + kgrp * 4 + r;
        const int col = bn + wno + n * 16 + lrow;
        float v = acc[m][n][r] + bias[col];
        if (EP == 0) Cf[(size_t)row * ldn + col] = v + kern[(row % KKK) * ldn + col];
        if (EP == 1) Cb[(size_t)row * ldn + col] = f2bf(gelu_f(v));
        if (EP == 2) Cf[(size_t)row * ldn + col] += v;
      }
}

// ---------------- row LayerNorm (fp32 in, bf16 out) ------------------------
__global__ __launch_bounds__(256) void row_ln_bf_kernel(
    const float* __restrict__ in, short* __restrict__ out,
    const float* __restrict__ g, const float* __restrict__ bb, float eps)
{
  const int row = blockIdx.x;
  const int tid = threadIdx.x;
  __shared__ float red[256];
  const size_t base = (size_t)row * CC;
  float x0 = in[base + tid];
  float x1 = in[base + tid + 256];
  float x2 = in[base + tid + 512];
  red[tid] = x0 + x1 + x2;
  __syncthreads();
  for (int st = 128; st > 0; st >>= 1) { if (tid < st) red[tid] += red[tid + st]; __syncthreads(); }
  float mean = red[0] * (1.0f / 768.0f);
  __syncthreads();
  float d0 = x0 - mean, d1 = x1 - mean, d2 = x2 - mean;
  red[tid] = d0 * d0 + d1 * d1 + d2 * d2;
  __syncthreads();
  for (int st = 128; st > 0; st >>= 1) { if (tid < st) red[tid] += red[tid + st]; __syncthreads(); }
  float rstd = rsqrtf(red[0] * (1.0f / 768.0f) + eps);
  out[base + tid]       = f2bf(d0 * rstd * g[tid]       + bb[tid]);
  out[base + tid + 256] = f2bf(d1 * rstd * g[tid + 256] + bb[tid + 256]);
  out[base + tid + 512] = f2bf(d2 * rstd * g[tid + 512] + bb[tid + 512]);
}

// ---------------- attention: bf16 scores in big; softmax + PV --------------
__global__ __launch_bounds__(256) void attn_kernel(
    const short* __restrict__ big,      // [32768][1664] bf16 (v|xq|scores)
    short* __restrict__ ca)             // [32][9][768] bf16
{
  const int b = blockIdx.x;
  const int h = blockIdx.y;
  const int tid = threadIdx.x;
  const int wave = tid >> 6, lane = tid & 63;
  __shared__ float sc[KKK][NN];
  __shared__ float part[4][KKK][HDD];
#pragma unroll
  for (int nn = 0; nn < 4; nn++) {
    const int n = tid + nn * 256;
    const short* sp = &big[(size_t)(b * NN + n) * KN2 + 1536 + h * 9];
#pragma unroll
    for (int q = 0; q < KKK; q++) sc[q][n] = bfbits2f(sp[q]);
  }
  __syncthreads();
  for (int q = wave; q < KKK; q += 4) {
    float m = -1e30f;
#pragma unroll
    for (int i = 0; i < 16; i++) m = fmaxf(m, sc[q][lane + i * 64]);
#pragma unroll
    for (int off = 32; off > 0; off >>= 1) m = fmaxf(m, __shfl_xor(m, off));
    float s = 0.f;
#pragma unroll
    for (int i = 0; i < 16; i++) {
      float e = expf(sc[q][lane + i * 64] - m);
      sc[q][lane + i * 64] = e;
      s += e;
    }
#pragma unroll
    for (int off = 32; off > 0; off >>= 1) s += __shfl_xor(s, off);
    float inv = 1.0f / s;
#pragma unroll
    for (int i = 0; i < 16; i++) sc[q][lane + i * 64] *= inv;
  }
  __syncthreads();
  const int d = tid & 63, prt = tid >> 6;
  float po[KKK];
#pragma unroll
  for (int q = 0; q < KKK; q++) po[q] = 0.f;
  const short* vbase = &big[(size_t)(b * NN) * KN2 + h * HDD + d];
  for (int n0 = prt * 256; n0 < prt * 256 + 256; n0 += 4) {
    f32x4 p[KKK];
#pragma unroll
    for (int q = 0; q < KKK; q++) p[q] = *(const f32x4*)&sc[q][n0];
#pragma unroll
    for (int j = 0; j < 4; j++) {
      float vf = bfbits2f(vbase[(size_t)(n0 + j) * KN2]);
#pragma unroll
      for (int q = 0; q < KKK; q++) po[q] += p[q][j] * vf;
    }
  }
#pragma unroll
  for (int q = 0; q < KKK; q++) part[prt][q][d] = po[q];
  __syncthreads();
  for (int i = tid; i < KKK * HDD; i += 256) {
    int q = i >> 6, dd = i & 63;
    ca[(size_t)(b * KKK + q) * CC + h * HDD + dd] =
        f2bf(part[0][q][dd] + part[1][q][dd] + part[2][q][dd] + part[3][q][dd]);
  }
}

// ---------------- token mixer (bf16 input), 16 j-chunks --------------------
__global__ __launch_bounds__(256) void token_mix_kernel(
    const short* __restrict__ ln1,     // [288][768] bf16
    const float* __restrict__ pm1_w,   // [9][1536]
    const float* __restrict__ pm1_b,   // [1536]
    const float* __restrict__ pm2_w,   // [1536][9]
    float* __restrict__ part)          // [TMC][32][9][768]
{
  const int tid = threadIdx.x;
  const int c = blockIdx.x * 256 + tid;
  const int b = blockIdx.y;
  const int jc = blockIdx.z;
  float u[KKK], o[KKK];
#pragma unroll
  for (int q = 0; q < KKK; q++) {
    u[q] = bfbits2f(ln1[(size_t)(b * KKK + q) * CC + c]);
    o[q] = 0.f;
  }
  const int j0 = jc * (PMDD / TMC);
  for (int j = j0; j < j0 + PMDD / TMC; j++) {
    float hs = pm1_b[j];
#pragma unroll
    for (int q = 0; q < KKK; q++) hs += u[q] * pm1_w[q * PMDD + j];
    float gv = gelu_f(hs);
    const float* p2 = &pm2_w[(size_t)j * KKK];
#pragma unroll
    for (int q = 0; q < KKK; q++) o[q] += gv * p2[q];
  }
  float* pp = &part[(size_t)((jc * BB + b) * KKK) * CC + c];
#pragma unroll
  for (int q = 0; q < KKK; q++) pp[(size_t)q * CC] = o[q];
}

// ---------------- token reduce + LN2 (bf16 LN output) ----------------------
__global__ __launch_bounds__(256) void token_reduce_ln_kernel(
    const float* __restrict__ part,    // [TMC][32][9][768]
    const float* __restrict__ pm2_b,   // [9]
    const float* __restrict__ g, const float* __restrict__ bb,
    float* __restrict__ w1,            // [288][768] (in/out)
    short* __restrict__ lnb)           // [288][768] bf16
{
  const int row = blockIdx.x;
  const int q = row % KKK;
  const int tid = threadIdx.x;
  __shared__ float red[256];
  const size_t base = (size_t)row * CC;
  float v[3];
#pragma unroll
  for (int j = 0; j < 3; j++) {
    const int c = tid + j * 256;
    float s = 0.f;
#pragma unroll
    for (int gg = 0; gg < TMC; gg++)
      s += part[(size_t)gg * BB * KKK * CC + base + c];
    v[j] = w1[base + c] + s + pm2_b[q];
    w1[base + c] = v[j];
  }
  red[tid] = v[0] + v[1] + v[2];
  __syncthreads();
  for (int st = 128; st > 0; st >>= 1) { if (tid < st) red[tid] += red[tid + st]; __syncthreads(); }
  float mean = red[0] * (1.0f / 768.0f);
  __syncthreads();
  float d0 = v[0] - mean, d1 = v[1] - mean, d2 = v[2] - mean;
  red[tid] = d0 * d0 + d1 * d1 + d2 * d2;
  __syncthreads();
  for (int st = 128; st > 0; st >>= 1) { if (tid < st) red[tid] += red[tid + st]; __syncthreads(); }
  float rstd = rsqrtf(red[0] * (1.0f / 768.0f) + 1e-5f);
  lnb[base + tid]       = f2bf(d0 * rstd * g[tid]       + bb[tid]);
  lnb[base + tid + 256] = f2bf(d1 * rstd * g[tid + 256] + bb[tid + 256]);
  lnb[base + tid + 512] = f2bf(d2 * rstd * g[tid + 512] + bb[tid + 512]);
}

// ---------------- conv: LDS-staged read-once, sliding window ---------------
__global__ __launch_bounds__(256) void conv_lds_kernel(
    const short* __restrict__ big,   // xq (bf16) at column offset 768
    const float* __restrict__ w1,    // [32][9][768] filters
    float* __restrict__ out)         // [32][1024][768] fp32
{
  __shared__ short rows[3][32][132];
  const int c0 = blockIdx.x * 128;
  const int b = blockIdx.y;
  const int y0 = blockIdx.z * 8;
  const int tid = threadIdx.x;
  const int xl = tid >> 3, cg = tid & 7;
  const int cl = tid & 127, xh = tid >> 7;
  float f[KKK];
#pragma unroll
  for (int q = 0; q < KKK; q++) f[q] = w1[(size_t)(b * KKK + q) * CC + c0 + cl];

#define LOAD_ROW(yy, slot)                                                     \
  {                                                                            \
    short* dst = &rows[slot][xl][cg * 16];                                     \
    if ((yy) >= 0 && (yy) < 32) {                                              \
      const short* src =                                                       \
          &big[(size_t)(b * NN + (yy) * 32 + xl) * KN2 + CC + c0 + cg * 16];   \
      *(bf16x8*)dst = *(const bf16x8*)src;                                     \
      *(bf16x8*)(dst + 8) = *(const bf16x8*)(src + 8);                         \
    } else {                                                                   \
      bf16x8 z = {0, 0, 0, 0, 0, 0, 0, 0};                                     \
      *(bf16x8*)dst = z;                                                       \
      *(bf16x8*)(dst + 8) = z;                                                 \
    }                                                                          \
  }

  int sPrev = 0, sCur = 1, sNext = 2;
  LOAD_ROW(y0 - 1, 0);
  LOAD_ROW(y0, 1);
  for (int y = y0; y < y0 + 8; ++y) {
    LOAD_ROW(y + 1, sNext);
    __syncthreads();
    const int xb = xh * 16;
    float v0[3], v1[3];
#pragma unroll
    for (int ky = 0; ky < 3; ky++) {
      const int s = (ky == 0) ? sPrev : (ky == 1 ? sCur : sNext);
      v1[ky] = bfbits2f(rows[s][xb][cl]);
      v0[ky] = (xb == 0) ? 0.f : bfbits2f(rows[s][xb - 1][cl]);
    }
    float* op = &out[(size_t)(b * NN + y * 32 + xb) * CC + c0 + cl];
#pragma unroll
    for (int i = 0; i < 16; i++) {
      const int x = xb + i;
      float v2[3];
#pragma unroll
      for (int ky = 0; ky < 3; ky++) {
        const int s = (ky == 0) ? sPrev : (ky == 1 ? sCur : sNext);
        v2[ky] = (x + 1 < 32) ? bfbits2f(rows[s][x + 1][cl]) : 0.f;
      }
      float acc = 0.f;
#pragma unroll
      for (int ky = 0; ky < 3; ky++)
        acc += f[ky * 3] * v0[ky] + f[ky * 3 + 1] * v1[ky] + f[ky * 3 + 2] * v2[ky];
      op[(size_t)i * CC] = acc;
#pragma unroll
      for (int ky = 0; ky < 3; ky++) { v0[ky] = v1[ky]; v1[ky] = v2[ky]; }
    }
    __syncthreads();
    const int t = sPrev; sPrev = sCur; sCur = sNext; sNext = t;
  }
#undef LOAD_ROW
}

// ---------------------------------------------------------------------------
extern "C" void kernel_launch(void* const* d_in, const int* in_sizes, int n_in,
                              void* d_out, int out_size, void* d_ws, size_t ws_size,
                              hipStream_t stream) {
  (void)in_sizes; (void)n_in; (void)out_size; (void)ws_size;
  const float* x       = (const float*)d_in[0];
  const float* kern    = (const float*)d_in[3];
  const float* ln_g    = (const float*)d_in[4];
  const float* ln_b    = (const float*)d_in[5];
  const float* kv_w    = (const float*)d_in[6];
  const float* proj_w  = (const float*)d_in[7];
  const float* proj_b  = (const float*)d_in[8];
  const float* projq_w = (const float*)d_in[9];
  const float* n1_g    = (const float*)d_in[10];
  const float* n1_b    = (const float*)d_in[11];
  const float* n2_g    = (const float*)d_in[12];
  const float* n2_b    = (const float*)d_in[13];
  const float* pm1_w   = (const float*)d_in[14];
  const float* pm1_b   = (const float*)d_in[15];
  const float* pm2_w   = (const float*)d_in[16];
  const float* pm2_b   = (const float*)d_in[17];
  const float* cm1_w   = (const float*)d_in[18];
  const float* cm1_b   = (const float*)d_in[19];
  const float* cm2_w   = (const float*)d_in[20];
  const float* cm2_b   = (const float*)d_in[21];
  float* out = (float*)d_out;

  uint8_t* ws = (uint8_t*)d_ws;
  short* Wt   = (short*)(ws);                    // 1664*768*2 = 2,555,904
  short* h1   = (short*)(ws);                    // ALIAS: 884,736 (Wt dead)
  short* big  = (short*)(ws + 3538944);          // 32768*1664*2 = 109,051,904
  short* cab  = (short*)(ws + 154561536);        // 442,368
  float* w1   = (float*)(ws + 155446272);        // 884,736
  short* ln1b = (short*)(ws + 156331008);        // 442,368
  short* ln2b = (short*)(ws + 156773376);        // 442,368 -> 157,215,744

  short* xb    = (short*)d_out;
  float* tpart = (float*)d_out;                  // [16][32][9][768] = 14.2 MB
  short* WpT   = (short*)((uint8_t*)d_out + 62914560);  // [768][768]
  short* Wc1T  = (short*)((uint8_t*)d_out + 64094208);  // [1536][768]
  short* Wc2T  = (short*)((uint8_t*)d_out + 66453504);  // [768][1536]

  prep_kernel<<<dim3(XBF_BLOCKS + WT_BLOCKS + WT2_BLOCKS + SW_BLOCKS), 256, 0, stream>>>(
      x, xb, kv_w, projq_w, Wt, proj_w, cm1_w, cm2_w, WpT, Wc1T, Wc2T,
      kern, ln_g, ln_b);
  gemm_bt_kernel<<<dim3((MM / 128) * (KN2 / 128)), 128, 0, stream>>>(xb, Wt, big);
  attn_kernel<<<dim3(BB, NHH), 256, 0, stream>>>(big, cab);
  mfma96_kernel<0><<<dim3(3, 6), 256, 0, stream>>>(cab, WpT, CC, CC,
                                                   proj_b, kern, w1, nullptr);
  row_ln_bf_kernel<<<dim3(BB * KKK), 256, 0, stream>>>(w1, ln1b, n1_g, n1_b, 1e-5f);
  token_mix_kernel<<<dim3(3, 32, TMC), 256, 0, stream>>>(ln1b, pm1_w, pm1_b, pm2_w, tpart);
  token_reduce_ln_kernel<<<dim3(BB * KKK), 256, 0, stream>>>(tpart, pm2_b,
                                                             n2_g, n2_b, w1, ln2b);
  mfma96_kernel<1><<<dim3(3, 12), 256, 0, stream>>>(ln2b, Wc1T, CC, CMDD,
                                                    cm1_b, nullptr, nullptr, h1);
  mfma96_kernel<2><<<dim3(3, 6), 256, 0, stream>>>(h1, Wc2T, CMDD, CC,
                                                   cm2_b, nullptr, w1, nullptr);
  conv_lds_kernel<<<dim3(6, 32, 4), 256, 0, stream>>>(big, w1, out);
}

// Round 18
// 320.829 us; speedup vs baseline: 1.1072x; 1.1072x over previous
//
#include <hip/hip_runtime.h>
#include <hip/hip_bf16.h>
#include <cstdint>
#include <cstddef>

typedef __attribute__((ext_vector_type(8))) short bf16x8;
typedef __attribute__((ext_vector_type(4))) float f32x4;

#define BB 32
#define NN 1024
#define CC 768
#define NHH 12
#define HDD 64
#define KKK 9
#define MM (BB * NN)   /* 32768 */
#define KN2 1664       /* v(768) | xq(768) | scores(108 pad 128) */
#define PMDD 1536
#define CMDD 1536
#define BK 64

#define XBF_BLOCKS 12288   /* MM*CC/(256*8) */
#define WT_BLOCKS 1152     /* 48 j-tiles x 24 c-tiles (v+xq = 1536 rows) */
#define WT2_BLOCKS 2880
#define SW_BLOCKS 128      /* 108 score rows + 20 zero-pad rows */
#define TMC 16             /* token-mix j-chunks */

__device__ __forceinline__ float bfbits2f(short s) {
  union { uint32_t u; float f; } cv;
  cv.u = ((uint32_t)(uint16_t)s) << 16;
  return cv.f;
}
__device__ __forceinline__ short f2bf(float f) {
  union { float f; uint32_t u; } cv;
  cv.f = f;
  uint32_t u = cv.u;
  uint32_t r = (u + 0x7fffu + ((u >> 16) & 1u)) >> 16;
  return (short)r;
}
__device__ __forceinline__ float gelu_f(float x) {
  return 0.5f * x * (1.0f + erff(x * 0.7071067811865476f));
}

typedef const __attribute__((address_space(1))) uint32_t* gp1_t;
typedef __attribute__((address_space(3))) uint32_t* lp3_t;
__device__ __forceinline__ void gload16(const short* g, const short* l) {
  __builtin_amdgcn_global_load_lds((gp1_t)(uintptr_t)(const void*)g,
                                   (lp3_t)(uint32_t)(uintptr_t)(const void*)l,
                                   16, 0, 0);
}

// ---- prep: x->bf16 + Wt build (v^T|xq^T|S_w) + small-W transposes ---------
__global__ __launch_bounds__(256) void prep_kernel(
    const float* __restrict__ x, short* __restrict__ xb,
    const float* __restrict__ kv_w, const float* __restrict__ projq_w,
    short* __restrict__ Wt,
    const float* __restrict__ proj_w, const float* __restrict__ cm1_w,
    const float* __restrict__ cm2_w,
    short* __restrict__ WpT, short* __restrict__ Wc1T, short* __restrict__ Wc2T,
    const float* __restrict__ kern, const float* __restrict__ ln_g,
    const float* __restrict__ ln_b)
{
  __shared__ float smem[1056];
  const int bx = blockIdx.x;
  const int tid = threadIdx.x;
  if (bx < XBF_BLOCKS) {
    const int i = (bx * 256 + tid) * 8;
    f32x4 a = *(const f32x4*)&x[i];
    f32x4 b = *(const f32x4*)&x[i + 4];
    bf16x8 o;
#pragma unroll
    for (int e = 0; e < 4; e++) { o[e] = f2bf(a[e]); o[e + 4] = f2bf(b[e]); }
    *(bf16x8*)&xb[i] = o;
    return;
  }
  if (bx < XBF_BLOCKS + WT_BLOCKS) {
    int b2 = bx - XBF_BLOCKS;
    int j0 = (b2 % 48) * 32;
    int c0 = (b2 / 48) * 32;
    const float* src; int ldj, jj;
    if (j0 < 768) { src = kv_w; ldj = 1536; jj = 768 + j0; }
    else          { src = projq_w; ldj = 768; jj = j0 - 768; }
    const int tx = tid & 31, ty = tid >> 5;
#pragma unroll
    for (int r = 0; r < 4; r++) {
      int cl = ty + r * 8;
      smem[cl * 33 + tx] = src[(size_t)(c0 + cl) * ldj + jj + tx];
    }
    __syncthreads();
#pragma unroll
    for (int r = 0; r < 4; r++) {
      int jl = ty + r * 8;
      Wt[(size_t)(j0 + jl) * CC + c0 + tx] = f2bf(smem[tx * 33 + jl]);
    }
    return;
  }
  if (bx < XBF_BLOCKS + WT_BLOCKS + WT2_BLOCKS) {
    int b2 = bx - XBF_BLOCKS - WT_BLOCKS;
    const float* src; short* dst; int ldj, ldc, j0, c0;
    if (b2 < 576)        { src = proj_w; dst = WpT;  ldj = 768;  ldc = 768;
                           j0 = (b2 % 24) * 32; c0 = (b2 / 24) * 32; }
    else if (b2 < 1728)  { b2 -= 576; src = cm1_w; dst = Wc1T; ldj = 1536; ldc = 768;
                           j0 = (b2 % 48) * 32; c0 = (b2 / 48) * 32; }
    else                 { b2 -= 1728; src = cm2_w; dst = Wc2T; ldj = 768; ldc = 1536;
                           j0 = (b2 % 24) * 32; c0 = (b2 / 24) * 32; }
    const int tx = tid & 31, ty = tid >> 5;
#pragma unroll
    for (int r = 0; r < 4; r++) {
      int cl = ty + r * 8;
      smem[cl * 33 + tx] = src[(size_t)(c0 + cl) * ldj + j0 + tx];
    }
    __syncthreads();
#pragma unroll
    for (int r = 0; r < 4; r++) {
      int jl = ty + r * 8;
      dst[(size_t)(j0 + jl) * ldc + c0 + tx] = f2bf(smem[tx * 33 + jl]);
    }
    return;
  }
  // SW blocks: Wt rows 1536+s = SCALE * (LN(kern)[q] row_h) @ Wk_h^T
  {
    const int s = bx - (XBF_BLOCKS + WT_BLOCKS + WT2_BLOCKS);
    if (s >= 108) {
      const size_t r = (size_t)(1536 + s) * CC;
      Wt[r + tid] = 0; Wt[r + tid + 256] = 0; Wt[r + tid + 512] = 0;
      return;
    }
    const int h = s / 9, q = s % 9;
    float* red = smem;
    const size_t base = (size_t)q * CC;
    float x0 = kern[base + tid];
    float x1 = kern[base + tid + 256];
    float x2 = kern[base + tid + 512];
    red[tid] = x0 + x1 + x2;
    __syncthreads();
    for (int st = 128; st > 0; st >>= 1) { if (tid < st) red[tid] += red[tid + st]; __syncthreads(); }
    float mean = red[0] * (1.0f / 768.0f);
    __syncthreads();
    float d0 = x0 - mean, d1 = x1 - mean, d2 = x2 - mean;
    red[tid] = d0 * d0 + d1 * d1 + d2 * d2;
    __syncthreads();
    for (int st = 128; st > 0; st >>= 1) { if (tid < st) red[tid] += red[tid + st]; __syncthreads(); }
    float rstd = rsqrtf(red[0] * (1.0f / 768.0f) + 1e-6f);
    __syncthreads();
    smem[tid]       = d0 * rstd * ln_g[tid]       + ln_b[tid];
    smem[tid + 256] = d1 * rstd * ln_g[tid + 256] + ln_b[tid + 256];
    smem[tid + 512] = d2 * rstd * ln_g[tid + 512] + ln_b[tid + 512];
    __syncthreads();
#pragma unroll
    for (int k = 0; k < 3; k++) {
      const int cc = tid + k * 256;
      const float* kw = &kv_w[(size_t)cc * 1536 + h * HDD];
      float acc = 0.f;
#pragma unroll
      for (int dd = 0; dd < HDD; dd++) acc += smem[h * HDD + dd] * kw[dd];
      Wt[(size_t)(1536 + s) * CC + cc] = f2bf(acc * 0.125f);
    }
  }
}

// ---------------- big GEMM: 128x128, BK=64, dbuf + counted vmcnt (proven) --
__global__ __launch_bounds__(256) void gemm_bt_kernel(
    const short* __restrict__ A,     // [MM][768] bf16
    const short* __restrict__ Bt,    // [1664][768] bf16 (B^T)
    short* __restrict__ C)           // [MM][1664] bf16 (v|xq|scores)
{
  __shared__ short As[2][128 * BK];
  __shared__ short Bs[2][128 * BK];
  const int tid = threadIdx.x;
  const int wave = tid >> 6, lane = tid & 63;
  const int lid = blockIdx.x;                    // 3328 = 8 * 416
  const int wid = (lid & 7) * 416 + (lid >> 3);
  const int bn = (wid % 13) * 128;
  const int bm = (wid / 13) * 128;
  const int wmo = (wave >> 1) * 64;
  const int wno = (wave & 1) * 64;
  const int lrow = lane & 15;
  const int kgrp = lane >> 4;
  const int sr = tid >> 3;
  const int ss = tid & 7;
  const int slotG = ss ^ (sr & 7);
  const short* gA = A + (size_t)(bm + sr) * CC + slotG * 8;
  const short* gB = Bt + (size_t)(bn + sr) * CC + slotG * 8;
  const int rs0 = kgrp ^ (lrow & 7);
  const int rs1 = (4 + kgrp) ^ (lrow & 7);
  f32x4 acc[4][4];
#pragma unroll
  for (int i = 0; i < 4; i++)
#pragma unroll
    for (int j = 0; j < 4; j++) acc[i][j] = (f32x4){0.f, 0.f, 0.f, 0.f};

#define STAGE(bb, k0)                                                          \
  {                                                                            \
    _Pragma("unroll")                                                          \
    for (int i = 0; i < 4; i++) {                                              \
      gload16(gA + (size_t)(i * 32) * CC + (k0),                               \
              &As[bb][(i * 32 + sr) * BK + ss * 8]);                           \
      gload16(gB + (size_t)(i * 32) * CC + (k0),                               \
              &Bs[bb][(i * 32 + sr) * BK + ss * 8]);                           \
    }                                                                          \
  }

  STAGE(0, 0);
  for (int t = 0; t < 12; ++t) {
    const int cur = t & 1;
    if (t < 11) STAGE(cur ^ 1, (t + 1) * BK);
    __builtin_amdgcn_sched_barrier(0);
    if (t < 11) asm volatile("s_waitcnt vmcnt(8)" ::: "memory");
    else        asm volatile("s_waitcnt vmcnt(0)" ::: "memory");
    __builtin_amdgcn_s_barrier();
    __builtin_amdgcn_sched_barrier(0);
#pragma unroll
    for (int kh = 0; kh < 2; kh++) {
      const int rs = kh ? rs1 : rs0;
      bf16x8 af[4], bfr[4];
#pragma unroll
      for (int i = 0; i < 4; i++)
        af[i] = *(const bf16x8*)&As[cur][(wmo + i * 16 + lrow) * BK + rs * 8];
#pragma unroll
      for (int j = 0; j < 4; j++)
        bfr[j] = *(const bf16x8*)&Bs[cur][(wno + j * 16 + lrow) * BK + rs * 8];
      __builtin_amdgcn_s_setprio(1);
#pragma unroll
      for (int i = 0; i < 4; i++)
#pragma unroll
        for (int j = 0; j < 4; j++)
          acc[i][j] = __builtin_amdgcn_mfma_f32_16x16x32_bf16(af[i], bfr[j], acc[i][j], 0, 0, 0);
      __builtin_amdgcn_s_setprio(0);
    }
    __builtin_amdgcn_sched_barrier(0);
    __builtin_amdgcn_s_barrier();
  }
#undef STAGE
#pragma unroll
  for (int i = 0; i < 4; i++)
#pragma unroll
    for (int j = 0; j < 4; j++)
#pragma unroll
      for (int r = 0; r < 4; r++) {
        const int row = bm + wmo + i * 16 + kgrp * 4 + r;
        const int col = bn + wno + j * 16 + lrow;
        C[(size_t)row * KN2 + col] = f2bf(acc[i][j][r]);
      }
}

// ---------------- mini MFMA GEMM: 96x128, BK=64, dbuf + counted vmcnt ------
template <int EP>
__global__ __launch_bounds__(256) void mfma96_kernel(
    const short* __restrict__ A,    // [288][K] bf16
    const short* __restrict__ Bt,   // [N][K] bf16
    int K, int ldn,
    const float* __restrict__ bias,
    const float* __restrict__ kern,
    float* __restrict__ Cf,
    short* __restrict__ Cb)
{
  __shared__ short As[2][96 * BK];
  __shared__ short Bs[2][128 * BK];
  const int tid = threadIdx.x;
  const int wave = tid >> 6, lane = tid & 63;
  const int bm = blockIdx.x * 96;
  const int bn = blockIdx.y * 128;
  const int wmo = (wave >> 1) * 48;
  const int wno = (wave & 1) * 64;
  const int lrow = lane & 15;
  const int kgrp = lane >> 4;
  const int sr = tid >> 3;
  const int ss = tid & 7;
  const int rs0 = kgrp ^ (lrow & 7);
  const int rs1 = (4 + kgrp) ^ (lrow & 7);
  f32x4 acc[3][4];
#pragma unroll
  for (int i = 0; i < 3; i++)
#pragma unroll
    for (int j = 0; j < 4; j++) acc[i][j] = (f32x4){0.f, 0.f, 0.f, 0.f};

#define STAGEM(bb, k0)                                                         \
  {                                                                            \
    _Pragma("unroll")                                                          \
    for (int i = 0; i < 3; i++) {                                              \
      const int r = i * 32 + sr;                                               \
      const int sg = ss ^ (r & 7);                                             \
      gload16(A + (size_t)(bm + r) * K + (k0) + sg * 8,                        \
              &As[bb][r * BK + ss * 8]);                                       \
    }                                                                          \
    _Pragma("unroll")                                                          \
    for (int i = 0; i < 4; i++) {                                              \
      const int r = i * 32 + sr;                                               \
      const int sg = ss ^ (r & 7);                                             \
      gload16(Bt + (size_t)(bn + r) * K + (k0) + sg * 8,                       \
              &Bs[bb][r * BK + ss * 8]);                                       \
    }                                                                          \
  }

  const int nt = K / BK;
  STAGEM(0, 0);
  for (int t = 0; t < nt; ++t) {
    const int cur = t & 1;
    if (t < nt - 1) STAGEM(cur ^ 1, (t + 1) * BK);
    __builtin_amdgcn_sched_barrier(0);
    if (t < nt - 1) asm volatile("s_waitcnt vmcnt(7)" ::: "memory");
    else            asm volatile("s_waitcnt vmcnt(0)" ::: "memory");
    __builtin_amdgcn_s_barrier();
    __builtin_amdgcn_sched_barrier(0);
#pragma unroll
    for (int kh = 0; kh < 2; kh++) {
      const int rs = kh ? rs1 : rs0;
      bf16x8 af[3], bfr[4];
#pragma unroll
      for (int m = 0; m < 3; m++)
        af[m] = *(const bf16x8*)&As[cur][(wmo + m * 16 + lrow) * BK + rs * 8];
#pragma unroll
      for (int n = 0; n < 4; n++)
        bfr[n] = *(const bf16x8*)&Bs[cur][(wno + n * 16 + lrow) * BK + rs * 8];
#pragma unroll
      for (int m = 0; m < 3; m++)
#pragma unroll
        for (int n = 0; n < 4; n++)
          acc[m][n] = __builtin_amdgcn_mfma_f32_16x16x32_bf16(af[m], bfr[n], acc[m][n], 0, 0, 0);
    }
    __builtin_amdgcn_sched_barrier(0);
    __builtin_amdgcn_s_barrier();
  }
#undef STAGEM
#pragma unroll
  for (int m = 0; m < 3; m++)
#pragma unroll
    for (int n = 0; n < 4; n++)
#pragma unroll
      for (int r = 0; r < 4; r++) {
        const int row = bm + wmo + m * 16 + kgrp * 4 + r;
        const int col = bn + wno + n * 16 + lrow;
        float v = acc[m][n][r] + bias[col];
        if (EP == 0) Cf[(size_t)row * ldn + col] = v + kern[(row % KKK) * ldn + col];
        if (EP == 1) Cb[(size_t)row * ldn + col] = f2bf(gelu_f(v));
        if (EP == 2) Cf[(size_t)row * ldn + col] += v;
      }
}

// ---------------- row LayerNorm (fp32 in, bf16 out) ------------------------
__global__ __launch_bounds__(256) void row_ln_bf_kernel(
    const float* __restrict__ in, short* __restrict__ out,
    const float* __restrict__ g, const float* __restrict__ bb, float eps)
{
  const int row = blockIdx.x;
  const int tid = threadIdx.x;
  __shared__ float red[256];
  const size_t base = (size_t)row * CC;
  float x0 = in[base + tid];
  float x1 = in[base + tid + 256];
  float x2 = in[base + tid + 512];
  red[tid] = x0 + x1 + x2;
  __syncthreads();
  for (int st = 128; st > 0; st >>= 1) { if (tid < st) red[tid] += red[tid + st]; __syncthreads(); }
  float mean = red[0] * (1.0f / 768.0f);
  __syncthreads();
  float d0 = x0 - mean, d1 = x1 - mean, d2 = x2 - mean;
  red[tid] = d0 * d0 + d1 * d1 + d2 * d2;
  __syncthreads();
  for (int st = 128; st > 0; st >>= 1) { if (tid < st) red[tid] += red[tid + st]; __syncthreads(); }
  float rstd = rsqrtf(red[0] * (1.0f / 768.0f) + eps);
  out[base + tid]       = f2bf(d0 * rstd * g[tid]       + bb[tid]);
  out[base + tid + 256] = f2bf(d1 * rstd * g[tid + 256] + bb[tid + 256]);
  out[base + tid + 512] = f2bf(d2 * rstd * g[tid + 512] + bb[tid + 512]);
}

// ---------------- attention: bf16 scores in big; softmax + PV --------------
__global__ __launch_bounds__(256) void attn_kernel(
    const short* __restrict__ big,      // [32768][1664] bf16 (v|xq|scores)
    short* __restrict__ ca)             // [32][9][768] bf16
{
  const int b = blockIdx.x;
  const int h = blockIdx.y;
  const int tid = threadIdx.x;
  const int wave = tid >> 6, lane = tid & 63;
  __shared__ float sc[KKK][NN];
  __shared__ float part[4][KKK][HDD];
#pragma unroll
  for (int nn = 0; nn < 4; nn++) {
    const int n = tid + nn * 256;
    const short* sp = &big[(size_t)(b * NN + n) * KN2 + 1536 + h * 9];
#pragma unroll
    for (int q = 0; q < KKK; q++) sc[q][n] = bfbits2f(sp[q]);
  }
  __syncthreads();
  for (int q = wave; q < KKK; q += 4) {
    float m = -1e30f;
#pragma unroll
    for (int i = 0; i < 16; i++) m = fmaxf(m, sc[q][lane + i * 64]);
#pragma unroll
    for (int off = 32; off > 0; off >>= 1) m = fmaxf(m, __shfl_xor(m, off));
    float s = 0.f;
#pragma unroll
    for (int i = 0; i < 16; i++) {
      float e = expf(sc[q][lane + i * 64] - m);
      sc[q][lane + i * 64] = e;
      s += e;
    }
#pragma unroll
    for (int off = 32; off > 0; off >>= 1) s += __shfl_xor(s, off);
    float inv = 1.0f / s;
#pragma unroll
    for (int i = 0; i < 16; i++) sc[q][lane + i * 64] *= inv;
  }
  __syncthreads();
  const int d = tid & 63, prt = tid >> 6;
  float po[KKK];
#pragma unroll
  for (int q = 0; q < KKK; q++) po[q] = 0.f;
  const short* vbase = &big[(size_t)(b * NN) * KN2 + h * HDD + d];
  for (int n0 = prt * 256; n0 < prt * 256 + 256; n0 += 4) {
    f32x4 p[KKK];
#pragma unroll
    for (int q = 0; q < KKK; q++) p[q] = *(const f32x4*)&sc[q][n0];
#pragma unroll
    for (int j = 0; j < 4; j++) {
      float vf = bfbits2f(vbase[(size_t)(n0 + j) * KN2]);
#pragma unroll
      for (int q = 0; q < KKK; q++) po[q] += p[q][j] * vf;
    }
  }
#pragma unroll
  for (int q = 0; q < KKK; q++) part[prt][q][d] = po[q];
  __syncthreads();
  for (int i = tid; i < KKK * HDD; i += 256) {
    int q = i >> 6, dd = i & 63;
    ca[(size_t)(b * KKK + q) * CC + h * HDD + dd] =
        f2bf(part[0][q][dd] + part[1][q][dd] + part[2][q][dd] + part[3][q][dd]);
  }
}

// ---------------- token mixer (bf16 input), 16 j-chunks --------------------
__global__ __launch_bounds__(256) void token_mix_kernel(
    const short* __restrict__ ln1,     // [288][768] bf16
    const float* __restrict__ pm1_w,   // [9][1536]
    const float* __restrict__ pm1_b,   // [1536]
    const float* __restrict__ pm2_w,   // [1536][9]
    float* __restrict__ part)          // [TMC][32][9][768]
{
  const int tid = threadIdx.x;
  const int c = blockIdx.x * 256 + tid;
  const int b = blockIdx.y;
  const int jc = blockIdx.z;
  float u[KKK], o[KKK];
#pragma unroll
  for (int q = 0; q < KKK; q++) {
    u[q] = bfbits2f(ln1[(size_t)(b * KKK + q) * CC + c]);
    o[q] = 0.f;
  }
  const int j0 = jc * (PMDD / TMC);
  for (int j = j0; j < j0 + PMDD / TMC; j++) {
    float hs = pm1_b[j];
#pragma unroll
    for (int q = 0; q < KKK; q++) hs += u[q] * pm1_w[q * PMDD + j];
    float gv = gelu_f(hs);
    const float* p2 = &pm2_w[(size_t)j * KKK];
#pragma unroll
    for (int q = 0; q < KKK; q++) o[q] += gv * p2[q];
  }
  float* pp = &part[(size_t)((jc * BB + b) * KKK) * CC + c];
#pragma unroll
  for (int q = 0; q < KKK; q++) pp[(size_t)q * CC] = o[q];
}

// ---------------- token reduce + LN2 (bf16 LN output) ----------------------
__global__ __launch_bounds__(256) void token_reduce_ln_kernel(
    const float* __restrict__ part,    // [TMC][32][9][768]
    const float* __restrict__ pm2_b,   // [9]
    const float* __restrict__ g, const float* __restrict__ bb,
    float* __restrict__ w1,            // [288][768] (in/out)
    short* __restrict__ lnb)           // [288][768] bf16
{
  const int row = blockIdx.x;
  const int q = row % KKK;
  const int tid = threadIdx.x;
  __shared__ float red[256];
  const size_t base = (size_t)row * CC;
  float v[3];
#pragma unroll
  for (int j = 0; j < 3; j++) {
    const int c = tid + j * 256;
    float s = 0.f;
#pragma unroll
    for (int gg = 0; gg < TMC; gg++)
      s += part[(size_t)gg * BB * KKK * CC + base + c];
    v[j] = w1[base + c] + s + pm2_b[q];
    w1[base + c] = v[j];
  }
  red[tid] = v[0] + v[1] + v[2];
  __syncthreads();
  for (int st = 128; st > 0; st >>= 1) { if (tid < st) red[tid] += red[tid + st]; __syncthreads(); }
  float mean = red[0] * (1.0f / 768.0f);
  __syncthreads();
  float d0 = v[0] - mean, d1 = v[1] - mean, d2 = v[2] - mean;
  red[tid] = d0 * d0 + d1 * d1 + d2 * d2;
  __syncthreads();
  for (int st = 128; st > 0; st >>= 1) { if (tid < st) red[tid] += red[tid + st]; __syncthreads(); }
  float rstd = rsqrtf(red[0] * (1.0f / 768.0f) + 1e-5f);
  lnb[base + tid]       = f2bf(d0 * rstd * g[tid]       + bb[tid]);
  lnb[base + tid + 256] = f2bf(d1 * rstd * g[tid + 256] + bb[tid + 256]);
  lnb[base + tid + 512] = f2bf(d2 * rstd * g[tid + 512] + bb[tid + 512]);
}

// ---------------- conv: LDS-staged read-once, sliding window ---------------
__global__ __launch_bounds__(256) void conv_lds_kernel(
    const short* __restrict__ big,   // xq (bf16) at column offset 768
    const float* __restrict__ w1,    // [32][9][768] filters
    float* __restrict__ out)         // [32][1024][768] fp32
{
  __shared__ short rows[3][32][132];
  const int c0 = blockIdx.x * 128;
  const int b = blockIdx.y;
  const int y0 = blockIdx.z * 8;
  const int tid = threadIdx.x;
  const int xl = tid >> 3, cg = tid & 7;
  const int cl = tid & 127, xh = tid >> 7;
  float f[KKK];
#pragma unroll
  for (int q = 0; q < KKK; q++) f[q] = w1[(size_t)(b * KKK + q) * CC + c0 + cl];

#define LOAD_ROW(yy, slot)                                                     \
  {                                                                            \
    short* dst = &rows[slot][xl][cg * 16];                                     \
    if ((yy) >= 0 && (yy) < 32) {                                              \
      const short* src =                                                       \
          &big[(size_t)(b * NN + (yy) * 32 + xl) * KN2 + CC + c0 + cg * 16];   \
      *(bf16x8*)dst = *(const bf16x8*)src;                                     \
      *(bf16x8*)(dst + 8) = *(const bf16x8*)(src + 8);                         \
    } else {                                                                   \
      bf16x8 z = {0, 0, 0, 0, 0, 0, 0, 0};                                     \
      *(bf16x8*)dst = z;                                                       \
      *(bf16x8*)(dst + 8) = z;                                                 \
    }                                                                          \
  }

  int sPrev = 0, sCur = 1, sNext = 2;
  LOAD_ROW(y0 - 1, 0);
  LOAD_ROW(y0, 1);
  for (int y = y0; y < y0 + 8; ++y) {
    LOAD_ROW(y + 1, sNext);
    __syncthreads();
    const int xb = xh * 16;
    float v0[3], v1[3];
#pragma unroll
    for (int ky = 0; ky < 3; ky++) {
      const int s = (ky == 0) ? sPrev : (ky == 1 ? sCur : sNext);
      v1[ky] = bfbits2f(rows[s][xb][cl]);
      v0[ky] = (xb == 0) ? 0.f : bfbits2f(rows[s][xb - 1][cl]);
    }
    float* op = &out[(size_t)(b * NN + y * 32 + xb) * CC + c0 + cl];
#pragma unroll
    for (int i = 0; i < 16; i++) {
      const int x = xb + i;
      float v2[3];
#pragma unroll
      for (int ky = 0; ky < 3; ky++) {
        const int s = (ky == 0) ? sPrev : (ky == 1 ? sCur : sNext);
        v2[ky] = (x + 1 < 32) ? bfbits2f(rows[s][x + 1][cl]) : 0.f;
      }
      float acc = 0.f;
#pragma unroll
      for (int ky = 0; ky < 3; ky++)
        acc += f[ky * 3] * v0[ky] + f[ky * 3 + 1] * v1[ky] + f[ky * 3 + 2] * v2[ky];
      op[(size_t)i * CC] = acc;
#pragma unroll
      for (int ky = 0; ky < 3; ky++) { v0[ky] = v1[ky]; v1[ky] = v2[ky]; }
    }
    __syncthreads();
    const int t = sPrev; sPrev = sCur; sCur = sNext; sNext = t;
  }
#undef LOAD_ROW
}

// ---------------------------------------------------------------------------
extern "C" void kernel_launch(void* const* d_in, const int* in_sizes, int n_in,
                              void* d_out, int out_size, void* d_ws, size_t ws_size,
                              hipStream_t stream) {
  (void)in_sizes; (void)n_in; (void)out_size; (void)ws_size;
  const float* x       = (const float*)d_in[0];
  const float* kern    = (const float*)d_in[3];
  const float* ln_g    = (const float*)d_in[4];
  const float* ln_b    = (const float*)d_in[5];
  const float* kv_w    = (const float*)d_in[6];
  const float* proj_w  = (const float*)d_in[7];
  const float* proj_b  = (const float*)d_in[8];
  const float* projq_w = (const float*)d_in[9];
  const float* n1_g    = (const float*)d_in[10];
  const float* n1_b    = (const float*)d_in[11];
  const float* n2_g    = (const float*)d_in[12];
  const float* n2_b    = (const float*)d_in[13];
  const float* pm1_w   = (const float*)d_in[14];
  const float* pm1_b   = (const float*)d_in[15];
  const float* pm2_w   = (const float*)d_in[16];
  const float* pm2_b   = (const float*)d_in[17];
  const float* cm1_w   = (const float*)d_in[18];
  const float* cm1_b   = (const float*)d_in[19];
  const float* cm2_w   = (const float*)d_in[20];
  const float* cm2_b   = (const float*)d_in[21];
  float* out = (float*)d_out;

  uint8_t* ws = (uint8_t*)d_ws;
  short* Wt   = (short*)(ws);                    // 1664*768*2 = 2,555,904
  short* h1   = (short*)(ws);                    // ALIAS: 884,736 (Wt dead)
  short* big  = (short*)(ws + 3538944);          // 32768*1664*2 = 109,051,904
  short* cab  = (short*)(ws + 154561536);        // 442,368
  float* w1   = (float*)(ws + 155446272);        // 884,736
  short* ln1b = (short*)(ws + 156331008);        // 442,368
  short* ln2b = (short*)(ws + 156773376);        // 442,368 -> 157,215,744

  short* xb    = (short*)d_out;
  float* tpart = (float*)d_out;                  // [16][32][9][768] = 14.2 MB
  short* WpT   = (short*)((uint8_t*)d_out + 62914560);  // [768][768]
  short* Wc1T  = (short*)((uint8_t*)d_out + 64094208);  // [1536][768]
  short* Wc2T  = (short*)((uint8_t*)d_out + 66453504);  // [768][1536]

  prep_kernel<<<dim3(XBF_BLOCKS + WT_BLOCKS + WT2_BLOCKS + SW_BLOCKS), 256, 0, stream>>>(
      x, xb, kv_w, projq_w, Wt, proj_w, cm1_w, cm2_w, WpT, Wc1T, Wc2T,
      kern, ln_g, ln_b);
  gemm_bt_kernel<<<dim3((MM / 128) * (KN2 / 128)), 256, 0, stream>>>(xb, Wt, big);
  attn_kernel<<<dim3(BB, NHH), 256, 0, stream>>>(big, cab);
  mfma96_kernel<0><<<dim3(3, 6), 256, 0, stream>>>(cab, WpT, CC, CC,
                                                   proj_b, kern, w1, nullptr);
  row_ln_bf_kernel<<<dim3(BB * KKK), 256, 0, stream>>>(w1, ln1b, n1_g, n1_b, 1e-5f);
  token_mix_kernel<<<dim3(3, 32, TMC), 256, 0, stream>>>(ln1b, pm1_w, pm1_b, pm2_w, tpart);
  token_reduce_ln_kernel<<<dim3(BB * KKK), 256, 0, stream>>>(tpart, pm2_b,
                                                             n2_g, n2_b, w1, ln2b);
  mfma96_kernel<1><<<dim3(3, 12), 256, 0, stream>>>(ln2b, Wc1T, CC, CMDD,
                                                    cm1_b, nullptr, nullptr, h1);
  mfma96_kernel<2><<<dim3(3, 6), 256, 0, stream>>>(h1, Wc2T, CMDD, CC,
                                                   cm2_b, nullptr, w1, nullptr);
  conv_lds_kernel<<<dim3(6, 32, 4), 256, 0, stream>>>(big, w1, out);
}

// Round 19
// 310.831 us; speedup vs baseline: 1.1428x; 1.0322x over previous
//
#include <hip/hip_runtime.h>
#include <hip/hip_bf16.h>
#include <cstdint>
#include <cstddef>

typedef __attribute__((ext_vector_type(8))) short bf16x8;
typedef __attribute__((ext_vector_type(4))) float f32x4;

#define BB 32
#define NN 1024
#define CC 768
#define NHH 12
#define HDD 64
#define KKK 9
#define MM (BB * NN)   /* 32768 */
#define KN2 1664       /* v(768) | xq(768) | scores(108 pad 128) */
#define PMDD 1536
#define CMDD 1536
#define BK 64

#define XBF_BLOCKS 12288   /* MM*CC/(256*8) */
#define WT_BLOCKS 1152     /* 48 j-tiles x 24 c-tiles (v+xq = 1536 rows) */
#define WT2_BLOCKS 2880
#define SW_BLOCKS 128      /* 108 score rows + 20 zero-pad rows */
#define TMC 16             /* token-mix j-chunks */

__device__ __forceinline__ float bfbits2f(short s) {
  union { uint32_t u; float f; } cv;
  cv.u = ((uint32_t)(uint16_t)s) << 16;
  return cv.f;
}
__device__ __forceinline__ short f2bf(float f) {
  union { float f; uint32_t u; } cv;
  cv.f = f;
  uint32_t u = cv.u;
  uint32_t r = (u + 0x7fffu + ((u >> 16) & 1u)) >> 16;
  return (short)r;
}
__device__ __forceinline__ float gelu_f(float x) {
  return 0.5f * x * (1.0f + erff(x * 0.7071067811865476f));
}

typedef const __attribute__((address_space(1))) uint32_t* gp1_t;
typedef __attribute__((address_space(3))) uint32_t* lp3_t;
__device__ __forceinline__ void gload16(const short* g, const short* l) {
  __builtin_amdgcn_global_load_lds((gp1_t)(uintptr_t)(const void*)g,
                                   (lp3_t)(uint32_t)(uintptr_t)(const void*)l,
                                   16, 0, 0);
}

// ---- prep: x->bf16 + Wt build (v^T|xq^T|S_w) + small-W transposes ---------
__global__ __launch_bounds__(256) void prep_kernel(
    const float* __restrict__ x, short* __restrict__ xb,
    const float* __restrict__ kv_w, const float* __restrict__ projq_w,
    short* __restrict__ Wt,
    const float* __restrict__ proj_w, const float* __restrict__ cm1_w,
    const float* __restrict__ cm2_w,
    short* __restrict__ WpT, short* __restrict__ Wc1T, short* __restrict__ Wc2T,
    const float* __restrict__ kern, const float* __restrict__ ln_g,
    const float* __restrict__ ln_b)
{
  __shared__ float smem[1056];
  const int bx = blockIdx.x;
  const int tid = threadIdx.x;
  if (bx < XBF_BLOCKS) {
    const int i = (bx * 256 + tid) * 8;
    f32x4 a = *(const f32x4*)&x[i];
    f32x4 b = *(const f32x4*)&x[i + 4];
    bf16x8 o;
#pragma unroll
    for (int e = 0; e < 4; e++) { o[e] = f2bf(a[e]); o[e + 4] = f2bf(b[e]); }
    *(bf16x8*)&xb[i] = o;
    return;
  }
  if (bx < XBF_BLOCKS + WT_BLOCKS) {
    int b2 = bx - XBF_BLOCKS;
    int j0 = (b2 % 48) * 32;
    int c0 = (b2 / 48) * 32;
    const float* src; int ldj, jj;
    if (j0 < 768) { src = kv_w; ldj = 1536; jj = 768 + j0; }
    else          { src = projq_w; ldj = 768; jj = j0 - 768; }
    const int tx = tid & 31, ty = tid >> 5;
#pragma unroll
    for (int r = 0; r < 4; r++) {
      int cl = ty + r * 8;
      smem[cl * 33 + tx] = src[(size_t)(c0 + cl) * ldj + jj + tx];
    }
    __syncthreads();
#pragma unroll
    for (int r = 0; r < 4; r++) {
      int jl = ty + r * 8;
      Wt[(size_t)(j0 + jl) * CC + c0 + tx] = f2bf(smem[tx * 33 + jl]);
    }
    return;
  }
  if (bx < XBF_BLOCKS + WT_BLOCKS + WT2_BLOCKS) {
    int b2 = bx - XBF_BLOCKS - WT_BLOCKS;
    const float* src; short* dst; int ldj, ldc, j0, c0;
    if (b2 < 576)        { src = proj_w; dst = WpT;  ldj = 768;  ldc = 768;
                           j0 = (b2 % 24) * 32; c0 = (b2 / 24) * 32; }
    else if (b2 < 1728)  { b2 -= 576; src = cm1_w; dst = Wc1T; ldj = 1536; ldc = 768;
                           j0 = (b2 % 48) * 32; c0 = (b2 / 48) * 32; }
    else                 { b2 -= 1728; src = cm2_w; dst = Wc2T; ldj = 768; ldc = 1536;
                           j0 = (b2 % 24) * 32; c0 = (b2 / 24) * 32; }
    const int tx = tid & 31, ty = tid >> 5;
#pragma unroll
    for (int r = 0; r < 4; r++) {
      int cl = ty + r * 8;
      smem[cl * 33 + tx] = src[(size_t)(c0 + cl) * ldj + j0 + tx];
    }
    __syncthreads();
#pragma unroll
    for (int r = 0; r < 4; r++) {
      int jl = ty + r * 8;
      dst[(size_t)(j0 + jl) * ldc + c0 + tx] = f2bf(smem[tx * 33 + jl]);
    }
    return;
  }
  // SW blocks: Wt rows 1536+s = SCALE * (LN(kern)[q] row_h) @ Wk_h^T
  {
    const int s = bx - (XBF_BLOCKS + WT_BLOCKS + WT2_BLOCKS);
    if (s >= 108) {
      const size_t r = (size_t)(1536 + s) * CC;
      Wt[r + tid] = 0; Wt[r + tid + 256] = 0; Wt[r + tid + 512] = 0;
      return;
    }
    const int h = s / 9, q = s % 9;
    float* red = smem;
    const size_t base = (size_t)q * CC;
    float x0 = kern[base + tid];
    float x1 = kern[base + tid + 256];
    float x2 = kern[base + tid + 512];
    red[tid] = x0 + x1 + x2;
    __syncthreads();
    for (int st = 128; st > 0; st >>= 1) { if (tid < st) red[tid] += red[tid + st]; __syncthreads(); }
    float mean = red[0] * (1.0f / 768.0f);
    __syncthreads();
    float d0 = x0 - mean, d1 = x1 - mean, d2 = x2 - mean;
    red[tid] = d0 * d0 + d1 * d1 + d2 * d2;
    __syncthreads();
    for (int st = 128; st > 0; st >>= 1) { if (tid < st) red[tid] += red[tid + st]; __syncthreads(); }
    float rstd = rsqrtf(red[0] * (1.0f / 768.0f) + 1e-6f);
    __syncthreads();
    smem[tid]       = d0 * rstd * ln_g[tid]       + ln_b[tid];
    smem[tid + 256] = d1 * rstd * ln_g[tid + 256] + ln_b[tid + 256];
    smem[tid + 512] = d2 * rstd * ln_g[tid + 512] + ln_b[tid + 512];
    __syncthreads();
#pragma unroll
    for (int k = 0; k < 3; k++) {
      const int cc = tid + k * 256;
      const float* kw = &kv_w[(size_t)cc * 1536 + h * HDD];
      float acc = 0.f;
#pragma unroll
      for (int dd = 0; dd < HDD; dd++) acc += smem[h * HDD + dd] * kw[dd];
      Wt[(size_t)(1536 + s) * CC + cc] = f2bf(acc * 0.125f);
    }
  }
}

// ---------------- big GEMM: 128x128, BK=64, dbuf + counted vmcnt (proven) --
__global__ __launch_bounds__(256) void gemm_bt_kernel(
    const short* __restrict__ A,     // [MM][768] bf16
    const short* __restrict__ Bt,    // [1664][768] bf16 (B^T)
    short* __restrict__ C)           // [MM][1664] bf16 (v|xq|scores)
{
  __shared__ short As[2][128 * BK];
  __shared__ short Bs[2][128 * BK];
  const int tid = threadIdx.x;
  const int wave = tid >> 6, lane = tid & 63;
  const int lid = blockIdx.x;                    // 3328 = 8 * 416
  const int wid = (lid & 7) * 416 + (lid >> 3);
  const int bn = (wid % 13) * 128;
  const int bm = (wid / 13) * 128;
  const int wmo = (wave >> 1) * 64;
  const int wno = (wave & 1) * 64;
  const int lrow = lane & 15;
  const int kgrp = lane >> 4;
  const int sr = tid >> 3;
  const int ss = tid & 7;
  const int slotG = ss ^ (sr & 7);
  const short* gA = A + (size_t)(bm + sr) * CC + slotG * 8;
  const short* gB = Bt + (size_t)(bn + sr) * CC + slotG * 8;
  const int rs0 = kgrp ^ (lrow & 7);
  const int rs1 = (4 + kgrp) ^ (lrow & 7);
  f32x4 acc[4][4];
#pragma unroll
  for (int i = 0; i < 4; i++)
#pragma unroll
    for (int j = 0; j < 4; j++) acc[i][j] = (f32x4){0.f, 0.f, 0.f, 0.f};

#define STAGE(bb, k0)                                                          \
  {                                                                            \
    _Pragma("unroll")                                                          \
    for (int i = 0; i < 4; i++) {                                              \
      gload16(gA + (size_t)(i * 32) * CC + (k0),                               \
              &As[bb][(i * 32 + sr) * BK + ss * 8]);                           \
      gload16(gB + (size_t)(i * 32) * CC + (k0),                               \
              &Bs[bb][(i * 32 + sr) * BK + ss * 8]);                           \
    }                                                                          \
  }

  STAGE(0, 0);
  for (int t = 0; t < 12; ++t) {
    const int cur = t & 1;
    if (t < 11) STAGE(cur ^ 1, (t + 1) * BK);
    __builtin_amdgcn_sched_barrier(0);
    if (t < 11) asm volatile("s_waitcnt vmcnt(8)" ::: "memory");
    else        asm volatile("s_waitcnt vmcnt(0)" ::: "memory");
    __builtin_amdgcn_s_barrier();
    __builtin_amdgcn_sched_barrier(0);
#pragma unroll
    for (int kh = 0; kh < 2; kh++) {
      const int rs = kh ? rs1 : rs0;
      bf16x8 af[4], bfr[4];
#pragma unroll
      for (int i = 0; i < 4; i++)
        af[i] = *(const bf16x8*)&As[cur][(wmo + i * 16 + lrow) * BK + rs * 8];
#pragma unroll
      for (int j = 0; j < 4; j++)
        bfr[j] = *(const bf16x8*)&Bs[cur][(wno + j * 16 + lrow) * BK + rs * 8];
      __builtin_amdgcn_s_setprio(1);
#pragma unroll
      for (int i = 0; i < 4; i++)
#pragma unroll
        for (int j = 0; j < 4; j++)
          acc[i][j] = __builtin_amdgcn_mfma_f32_16x16x32_bf16(af[i], bfr[j], acc[i][j], 0, 0, 0);
      __builtin_amdgcn_s_setprio(0);
    }
    __builtin_amdgcn_sched_barrier(0);
    __builtin_amdgcn_s_barrier();
  }
#undef STAGE
#pragma unroll
  for (int i = 0; i < 4; i++)
#pragma unroll
    for (int j = 0; j < 4; j++)
#pragma unroll
      for (int r = 0; r < 4; r++) {
        const int row = bm + wmo + i * 16 + kgrp * 4 + r;
        const int col = bn + wno + j * 16 + lrow;
        C[(size_t)row * KN2 + col] = f2bf(acc[i][j][r]);
      }
}

// ---------------- mini MFMA GEMM: 96x128, BK=64, dbuf + counted vmcnt ------
template <int EP>
__global__ __launch_bounds__(256) void mfma96_kernel(
    const short* __restrict__ A,    // [288][K] bf16
    const short* __restrict__ Bt,   // [N][K] bf16
    int K, int ldn,
    const float* __restrict__ bias,
    const float* __restrict__ kern,
    float* __restrict__ Cf,
    short* __restrict__ Cb)
{
  __shared__ short As[2][96 * BK];
  __shared__ short Bs[2][128 * BK];
  const int tid = threadIdx.x;
  const int wave = tid >> 6, lane = tid & 63;
  const int bm = blockIdx.x * 96;
  const int bn = blockIdx.y * 128;
  const int wmo = (wave >> 1) * 48;
  const int wno = (wave & 1) * 64;
  const int lrow = lane & 15;
  const int kgrp = lane >> 4;
  const int sr = tid >> 3;
  const int ss = tid & 7;
  const int rs0 = kgrp ^ (lrow & 7);
  const int rs1 = (4 + kgrp) ^ (lrow & 7);
  f32x4 acc[3][4];
#pragma unroll
  for (int i = 0; i < 3; i++)
#pragma unroll
    for (int j = 0; j < 4; j++) acc[i][j] = (f32x4){0.f, 0.f, 0.f, 0.f};

#define STAGEM(bb, k0)                                                         \
  {                                                                            \
    _Pragma("unroll")                                                          \
    for (int i = 0; i < 3; i++) {                                              \
      const int r = i * 32 + sr;                                               \
      const int sg = ss ^ (r & 7);                                             \
      gload16(A + (size_t)(bm + r) * K + (k0) + sg * 8,                        \
              &As[bb][r * BK + ss * 8]);                                       \
    }                                                                          \
    _Pragma("unroll")                                                          \
    for (int i = 0; i < 4; i++) {                                              \
      const int r = i * 32 + sr;                                               \
      const int sg = ss ^ (r & 7);                                             \
      gload16(Bt + (size_t)(bn + r) * K + (k0) + sg * 8,                       \
              &Bs[bb][r * BK + ss * 8]);                                       \
    }                                                                          \
  }

  const int nt = K / BK;
  STAGEM(0, 0);
  for (int t = 0; t < nt; ++t) {
    const int cur = t & 1;
    if (t < nt - 1) STAGEM(cur ^ 1, (t + 1) * BK);
    __builtin_amdgcn_sched_barrier(0);
    if (t < nt - 1) asm volatile("s_waitcnt vmcnt(7)" ::: "memory");
    else            asm volatile("s_waitcnt vmcnt(0)" ::: "memory");
    __builtin_amdgcn_s_barrier();
    __builtin_amdgcn_sched_barrier(0);
#pragma unroll
    for (int kh = 0; kh < 2; kh++) {
      const int rs = kh ? rs1 : rs0;
      bf16x8 af[3], bfr[4];
#pragma unroll
      for (int m = 0; m < 3; m++)
        af[m] = *(const bf16x8*)&As[cur][(wmo + m * 16 + lrow) * BK + rs * 8];
#pragma unroll
      for (int n = 0; n < 4; n++)
        bfr[n] = *(const bf16x8*)&Bs[cur][(wno + n * 16 + lrow) * BK + rs * 8];
#pragma unroll
      for (int m = 0; m < 3; m++)
#pragma unroll
        for (int n = 0; n < 4; n++)
          acc[m][n] = __builtin_amdgcn_mfma_f32_16x16x32_bf16(af[m], bfr[n], acc[m][n], 0, 0, 0);
    }
    __builtin_amdgcn_sched_barrier(0);
    __builtin_amdgcn_s_barrier();
  }
#undef STAGEM
#pragma unroll
  for (int m = 0; m < 3; m++)
#pragma unroll
    for (int n = 0; n < 4; n++)
#pragma unroll
      for (int r = 0; r < 4; r++) {
        const int row = bm + wmo + m * 16 + kgrp * 4 + r;
        const int col = bn + wno + n * 16 + lrow;
        float v = acc[m][n][r] + bias[col];
        if (EP == 0) Cf[(size_t)row * ldn + col] = v + kern[(row % KKK) * ldn + col];
        if (EP == 1) Cb[(size_t)row * ldn + col] = f2bf(gelu_f(v));
        if (EP == 2) Cf[(size_t)row * ldn + col] += v;
      }
}

// ---------------- row LayerNorm (fp32 in, bf16 out) ------------------------
__global__ __launch_bounds__(256) void row_ln_bf_kernel(
    const float* __restrict__ in, short* __restrict__ out,
    const float* __restrict__ g, const float* __restrict__ bb, float eps)
{
  const int row = blockIdx.x;
  const int tid = threadIdx.x;
  __shared__ float red[256];
  const size_t base = (size_t)row * CC;
  float x0 = in[base + tid];
  float x1 = in[base + tid + 256];
  float x2 = in[base + tid + 512];
  red[tid] = x0 + x1 + x2;
  __syncthreads();
  for (int st = 128; st > 0; st >>= 1) { if (tid < st) red[tid] += red[tid + st]; __syncthreads(); }
  float mean = red[0] * (1.0f / 768.0f);
  __syncthreads();
  float d0 = x0 - mean, d1 = x1 - mean, d2 = x2 - mean;
  red[tid] = d0 * d0 + d1 * d1 + d2 * d2;
  __syncthreads();
  for (int st = 128; st > 0; st >>= 1) { if (tid < st) red[tid] += red[tid + st]; __syncthreads(); }
  float rstd = rsqrtf(red[0] * (1.0f / 768.0f) + eps);
  out[base + tid]       = f2bf(d0 * rstd * g[tid]       + bb[tid]);
  out[base + tid + 256] = f2bf(d1 * rstd * g[tid + 256] + bb[tid + 256]);
  out[base + tid + 512] = f2bf(d2 * rstd * g[tid + 512] + bb[tid + 512]);
}

// ---------------- attention: 512 threads / 8 waves per (b,h) ---------------
__global__ __launch_bounds__(512) void attn_kernel(
    const short* __restrict__ big,      // [32768][1664] bf16 (v|xq|scores)
    short* __restrict__ ca)             // [32][9][768] bf16
{
  const int b = blockIdx.x;
  const int h = blockIdx.y;
  const int tid = threadIdx.x;
  const int wave = tid >> 6, lane = tid & 63;
  __shared__ float sc[KKK][NN];
  __shared__ float part[8][KKK][HDD];
#pragma unroll
  for (int nn = 0; nn < 2; nn++) {
    const int n = tid + nn * 512;
    const short* sp = &big[(size_t)(b * NN + n) * KN2 + 1536 + h * 9];
#pragma unroll
    for (int q = 0; q < KKK; q++) sc[q][n] = bfbits2f(sp[q]);
  }
  __syncthreads();
  for (int q = wave; q < KKK; q += 8) {
    float m = -1e30f;
#pragma unroll
    for (int i = 0; i < 16; i++) m = fmaxf(m, sc[q][lane + i * 64]);
#pragma unroll
    for (int off = 32; off > 0; off >>= 1) m = fmaxf(m, __shfl_xor(m, off));
    float s = 0.f;
#pragma unroll
    for (int i = 0; i < 16; i++) {
      float e = expf(sc[q][lane + i * 64] - m);
      sc[q][lane + i * 64] = e;
      s += e;
    }
#pragma unroll
    for (int off = 32; off > 0; off >>= 1) s += __shfl_xor(s, off);
    float inv = 1.0f / s;
#pragma unroll
    for (int i = 0; i < 16; i++) sc[q][lane + i * 64] *= inv;
  }
  __syncthreads();
  const int d = tid & 63, prt = tid >> 6;   // prt 0..7, 128 n each
  float po[KKK];
#pragma unroll
  for (int q = 0; q < KKK; q++) po[q] = 0.f;
  const short* vbase = &big[(size_t)(b * NN) * KN2 + h * HDD + d];
  for (int n0 = prt * 128; n0 < prt * 128 + 128; n0 += 4) {
    f32x4 p[KKK];
#pragma unroll
    for (int q = 0; q < KKK; q++) p[q] = *(const f32x4*)&sc[q][n0];
#pragma unroll
    for (int j = 0; j < 4; j++) {
      float vf = bfbits2f(vbase[(size_t)(n0 + j) * KN2]);
#pragma unroll
      for (int q = 0; q < KKK; q++) po[q] += p[q][j] * vf;
    }
  }
#pragma unroll
  for (int q = 0; q < KKK; q++) part[prt][q][d] = po[q];
  __syncthreads();
  for (int i = tid; i < KKK * HDD; i += 512) {
    int q = i >> 6, dd = i & 63;
    float s = 0.f;
#pragma unroll
    for (int g = 0; g < 8; g++) s += part[g][q][dd];
    ca[(size_t)(b * KKK + q) * CC + h * HDD + dd] = f2bf(s);
  }
}

// ---------------- token mixer (bf16 input), 16 j-chunks --------------------
__global__ __launch_bounds__(256) void token_mix_kernel(
    const short* __restrict__ ln1,     // [288][768] bf16
    const float* __restrict__ pm1_w,   // [9][1536]
    const float* __restrict__ pm1_b,   // [1536]
    const float* __restrict__ pm2_w,   // [1536][9]
    float* __restrict__ part)          // [TMC][32][9][768]
{
  const int tid = threadIdx.x;
  const int c = blockIdx.x * 256 + tid;
  const int b = blockIdx.y;
  const int jc = blockIdx.z;
  float u[KKK], o[KKK];
#pragma unroll
  for (int q = 0; q < KKK; q++) {
    u[q] = bfbits2f(ln1[(size_t)(b * KKK + q) * CC + c]);
    o[q] = 0.f;
  }
  const int j0 = jc * (PMDD / TMC);
  for (int j = j0; j < j0 + PMDD / TMC; j++) {
    float hs = pm1_b[j];
#pragma unroll
    for (int q = 0; q < KKK; q++) hs += u[q] * pm1_w[q * PMDD + j];
    float gv = gelu_f(hs);
    const float* p2 = &pm2_w[(size_t)j * KKK];
#pragma unroll
    for (int q = 0; q < KKK; q++) o[q] += gv * p2[q];
  }
  float* pp = &part[(size_t)((jc * BB + b) * KKK) * CC + c];
#pragma unroll
  for (int q = 0; q < KKK; q++) pp[(size_t)q * CC] = o[q];
}

// ---------------- token reduce + LN2 (bf16 LN output) ----------------------
__global__ __launch_bounds__(256) void token_reduce_ln_kernel(
    const float* __restrict__ part,    // [TMC][32][9][768]
    const float* __restrict__ pm2_b,   // [9]
    const float* __restrict__ g, const float* __restrict__ bb,
    float* __restrict__ w1,            // [288][768] (in/out)
    short* __restrict__ lnb)           // [288][768] bf16
{
  const int row = blockIdx.x;
  const int q = row % KKK;
  const int tid = threadIdx.x;
  __shared__ float red[256];
  const size_t base = (size_t)row * CC;
  float v[3];
#pragma unroll
  for (int j = 0; j < 3; j++) {
    const int c = tid + j * 256;
    float s = 0.f;
#pragma unroll
    for (int gg = 0; gg < TMC; gg++)
      s += part[(size_t)gg * BB * KKK * CC + base + c];
    v[j] = w1[base + c] + s + pm2_b[q];
    w1[base + c] = v[j];
  }
  red[tid] = v[0] + v[1] + v[2];
  __syncthreads();
  for (int st = 128; st > 0; st >>= 1) { if (tid < st) red[tid] += red[tid + st]; __syncthreads(); }
  float mean = red[0] * (1.0f / 768.0f);
  __syncthreads();
  float d0 = v[0] - mean, d1 = v[1] - mean, d2 = v[2] - mean;
  red[tid] = d0 * d0 + d1 * d1 + d2 * d2;
  __syncthreads();
  for (int st = 128; st > 0; st >>= 1) { if (tid < st) red[tid] += red[tid + st]; __syncthreads(); }
  float rstd = rsqrtf(red[0] * (1.0f / 768.0f) + 1e-5f);
  lnb[base + tid]       = f2bf(d0 * rstd * g[tid]       + bb[tid]);
  lnb[base + tid + 256] = f2bf(d1 * rstd * g[tid + 256] + bb[tid + 256]);
  lnb[base + tid + 512] = f2bf(d2 * rstd * g[tid + 512] + bb[tid + 512]);
}

// ---------------- conv: LDS-staged read-once, sliding window ---------------
__global__ __launch_bounds__(256) void conv_lds_kernel(
    const short* __restrict__ big,   // xq (bf16) at column offset 768
    const float* __restrict__ w1,    // [32][9][768] filters
    float* __restrict__ out)         // [32][1024][768] fp32
{
  __shared__ short rows[3][32][132];
  const int c0 = blockIdx.x * 128;
  const int b = blockIdx.y;
  const int y0 = blockIdx.z * 8;
  const int tid = threadIdx.x;
  const int xl = tid >> 3, cg = tid & 7;
  const int cl = tid & 127, xh = tid >> 7;
  float f[KKK];
#pragma unroll
  for (int q = 0; q < KKK; q++) f[q] = w1[(size_t)(b * KKK + q) * CC + c0 + cl];

#define LOAD_ROW(yy, slot)                                                     \
  {                                                                            \
    short* dst = &rows[slot][xl][cg * 16];                                     \
    if ((yy) >= 0 && (yy) < 32) {                                              \
      const short* src =                                                       \
          &big[(size_t)(b * NN + (yy) * 32 + xl) * KN2 + CC + c0 + cg * 16];   \
      *(bf16x8*)dst = *(const bf16x8*)src;                                     \
      *(bf16x8*)(dst + 8) = *(const bf16x8*)(src + 8);                         \
    } else {                                                                   \
      bf16x8 z = {0, 0, 0, 0, 0, 0, 0, 0};                                     \
      *(bf16x8*)dst = z;                                                       \
      *(bf16x8*)(dst + 8) = z;                                                 \
    }                                                                          \
  }

  int sPrev = 0, sCur = 1, sNext = 2;
  LOAD_ROW(y0 - 1, 0);
  LOAD_ROW(y0, 1);
  for (int y = y0; y < y0 + 8; ++y) {
    LOAD_ROW(y + 1, sNext);
    __syncthreads();
    const int xb = xh * 16;
    float v0[3], v1[3];
#pragma unroll
    for (int ky = 0; ky < 3; ky++) {
      const int s = (ky == 0) ? sPrev : (ky == 1 ? sCur : sNext);
      v1[ky] = bfbits2f(rows[s][xb][cl]);
      v0[ky] = (xb == 0) ? 0.f : bfbits2f(rows[s][xb - 1][cl]);
    }
    float* op = &out[(size_t)(b * NN + y * 32 + xb) * CC + c0 + cl];
#pragma unroll
    for (int i = 0; i < 16; i++) {
      const int x = xb + i;
      float v2[3];
#pragma unroll
      for (int ky = 0; ky < 3; ky++) {
        const int s = (ky == 0) ? sPrev : (ky == 1 ? sCur : sNext);
        v2[ky] = (x + 1 < 32) ? bfbits2f(rows[s][x + 1][cl]) : 0.f;
      }
      float acc = 0.f;
#pragma unroll
      for (int ky = 0; ky < 3; ky++)
        acc += f[ky * 3] * v0[ky] + f[ky * 3 + 1] * v1[ky] + f[ky * 3 + 2] * v2[ky];
      op[(size_t)i * CC] = acc;
#pragma unroll
      for (int ky = 0; ky < 3; ky++) { v0[ky] = v1[ky]; v1[ky] = v2[ky]; }
    }
    __syncthreads();
    const int t = sPrev; sPrev = sCur; sCur = sNext; sNext = t;
  }
#undef LOAD_ROW
}

// ---------------------------------------------------------------------------
extern "C" void kernel_launch(void* const* d_in, const int* in_sizes, int n_in,
                              void* d_out, int out_size, void* d_ws, size_t ws_size,
                              hipStream_t stream) {
  (void)in_sizes; (void)n_in; (void)out_size; (void)ws_size;
  const float* x       = (const float*)d_in[0];
  const float* kern    = (const float*)d_in[3];
  const float* ln_g    = (const float*)d_in[4];
  const float* ln_b    = (const float*)d_in[5];
  const float* kv_w    = (const float*)d_in[6];
  const float* proj_w  = (const float*)d_in[7];
  const float* proj_b  = (const float*)d_in[8];
  const float* projq_w = (const float*)d_in[9];
  const float* n1_g    = (const float*)d_in[10];
  const float* n1_b    = (const float*)d_in[11];
  const float* n2_g    = (const float*)d_in[12];
  const float* n2_b    = (const float*)d_in[13];
  const float* pm1_w   = (const float*)d_in[14];
  const float* pm1_b   = (const float*)d_in[15];
  const float* pm2_w   = (const float*)d_in[16];
  const float* pm2_b   = (const float*)d_in[17];
  const float* cm1_w   = (const float*)d_in[18];
  const float* cm1_b   = (const float*)d_in[19];
  const float* cm2_w   = (const float*)d_in[20];
  const float* cm2_b   = (const float*)d_in[21];
  float* out = (float*)d_out;

  uint8_t* ws = (uint8_t*)d_ws;
  short* Wt   = (short*)(ws);                    // 1664*768*2 = 2,555,904
  short* h1   = (short*)(ws);                    // ALIAS: 884,736 (Wt dead)
  short* big  = (short*)(ws + 3538944);          // 32768*1664*2 = 109,051,904
  short* cab  = (short*)(ws + 154561536);        // 442,368
  float* w1   = (float*)(ws + 155446272);        // 884,736
  short* ln1b = (short*)(ws + 156331008);        // 442,368
  short* ln2b = (short*)(ws + 156773376);        // 442,368 -> 157,215,744

  short* xb    = (short*)d_out;
  float* tpart = (float*)d_out;                  // [16][32][9][768] = 14.2 MB
  short* WpT   = (short*)((uint8_t*)d_out + 62914560);  // [768][768]
  short* Wc1T  = (short*)((uint8_t*)d_out + 64094208);  // [1536][768]
  short* Wc2T  = (short*)((uint8_t*)d_out + 66453504);  // [768][1536]

  prep_kernel<<<dim3(XBF_BLOCKS + WT_BLOCKS + WT2_BLOCKS + SW_BLOCKS), 256, 0, stream>>>(
      x, xb, kv_w, projq_w, Wt, proj_w, cm1_w, cm2_w, WpT, Wc1T, Wc2T,
      kern, ln_g, ln_b);
  gemm_bt_kernel<<<dim3((MM / 128) * (KN2 / 128)), 256, 0, stream>>>(xb, Wt, big);
  attn_kernel<<<dim3(BB, NHH), 512, 0, stream>>>(big, cab);
  mfma96_kernel<0><<<dim3(3, 6), 256, 0, stream>>>(cab, WpT, CC, CC,
                                                   proj_b, kern, w1, nullptr);
  row_ln_bf_kernel<<<dim3(BB * KKK), 256, 0, stream>>>(w1, ln1b, n1_g, n1_b, 1e-5f);
  token_mix_kernel<<<dim3(3, 32, TMC), 256, 0, stream>>>(ln1b, pm1_w, pm1_b, pm2_w, tpart);
  token_reduce_ln_kernel<<<dim3(BB * KKK), 256, 0, stream>>>(tpart, pm2_b,
                                                             n2_g, n2_b, w1, ln2b);
  mfma96_kernel<1><<<dim3(3, 12), 256, 0, stream>>>(ln2b, Wc1T, CC, CMDD,
                                                    cm1_b, nullptr, nullptr, h1);
  mfma96_kernel<2><<<dim3(3, 6), 256, 0, stream>>>(h1, Wc2T, CMDD, CC,
                                                   cm2_b, nullptr, w1, nullptr);
  conv_lds_kernel<<<dim3(6, 32, 4), 256, 0, stream>>>(big, w1, out);
}